// Round 3
// baseline (564.129 us; speedup 1.0000x reference)
//
#include <hip/hip_runtime.h>
#include <hip/hip_fp16.h>
#include <hip/hip_bf16.h>

#define SLOPE 0.2f

// ---------------------------------------------------------------------------
// attn = feat_rel @ W_rel + b_rel   (1 block, 256 threads, one col each)
// ---------------------------------------------------------------------------
__global__ void attn_kernel(const float* __restrict__ feat_rel,
                            const float* __restrict__ W_rel,
                            const float* __restrict__ b_rel,
                            float* __restrict__ attn) {
    int j = threadIdx.x;            // 0..255
    float acc = b_rel[j];
    for (int d = 0; d < 128; ++d)
        acc = fmaf(feat_rel[d], W_rel[d * 256 + j], acc);
    attn[j] = acc;
}

// ---------------------------------------------------------------------------
// Fused GEMM + per-head attention-scalar epilogue.
// Block = 256 threads, computes a 64-row x 128-col tile of f = feat@W + b.
// Thread t: rt = t>>4 (4 rows rt*4..), ct = t&15 (8 cols ct*8..): 4x8 microtile.
// Writes f (fp16, optional) and e[row][head] = sum_d f[row][h*16+d]*attn[h*32+attn_off+d].
// ---------------------------------------------------------------------------
__global__ __launch_bounds__(256) void gemm_el_kernel(
    const float* __restrict__ feat, const float* __restrict__ W,
    const float* __restrict__ bias, const float* __restrict__ attn,
    int attn_off, __half* __restrict__ f_out, float* __restrict__ e_out,
    int M)
{
    __shared__ float sA[64][68];    // [k][row], padded stride 68
    __shared__ float sW[64][128];   // [k][col]

    int t  = threadIdx.x;
    int rt = t >> 4;
    int ct = t & 15;
    int row0 = blockIdx.x * 64;

    float acc[4][8];
#pragma unroll
    for (int r = 0; r < 4; ++r)
#pragma unroll
        for (int j = 0; j < 8; ++j) acc[r][j] = 0.f;

    for (int kc = 0; kc < 2; ++kc) {
        int k0 = kc * 64;
        // stage A tile (64 rows x 64 k), transposed into sA[k][row]
        {
            int rr = t >> 4;        // 0..15
            int k4 = t & 15;        // float4 index within the 64-k chunk
#pragma unroll
            for (int i = 0; i < 4; ++i) {
                int row = rr + i * 16;
                int grow = row0 + row;
                float4 v = {0.f, 0.f, 0.f, 0.f};
                if (grow < M)
                    v = *(const float4*)(feat + (size_t)grow * 128 + k0 + k4 * 4);
                sA[k4 * 4 + 0][row] = v.x;
                sA[k4 * 4 + 1][row] = v.y;
                sA[k4 * 4 + 2][row] = v.z;
                sA[k4 * 4 + 3][row] = v.w;
            }
        }
        // stage W chunk (64 k x 128 cols)
        {
#pragma unroll
            for (int i = 0; i < 8; ++i) {
                int idx = t + i * 256;      // 0..2047 float4s
                int k = idx >> 5, j4 = idx & 31;
                *(float4*)&sW[k][j4 * 4] =
                    *(const float4*)(W + (size_t)(k0 + k) * 128 + j4 * 4);
            }
        }
        __syncthreads();
#pragma unroll 4
        for (int kk = 0; kk < 64; ++kk) {
            float4 a  = *(const float4*)&sA[kk][rt * 4];
            float4 b0 = *(const float4*)&sW[kk][ct * 8];
            float4 b1 = *(const float4*)&sW[kk][ct * 8 + 4];
            float av[4]  = {a.x, a.y, a.z, a.w};
            float bv[8]  = {b0.x, b0.y, b0.z, b0.w, b1.x, b1.y, b1.z, b1.w};
#pragma unroll
            for (int r = 0; r < 4; ++r)
#pragma unroll
                for (int j = 0; j < 8; ++j)
                    acc[r][j] = fmaf(av[r], bv[j], acc[r][j]);
        }
        __syncthreads();
    }

    // epilogue: bias, attention partial dot, fp16 store
    int h    = ct >> 1;             // head (16 cols per head, 8 cols per thread)
    int doff = (ct & 1) * 8;        // offset within head
    float bv[8], av[8];
#pragma unroll
    for (int j = 0; j < 8; ++j) {
        bv[j] = bias[ct * 8 + j];
        av[j] = attn[h * 32 + attn_off + doff + j];
    }
#pragma unroll
    for (int r = 0; r < 4; ++r) {
        int grow = row0 + rt * 4 + r;
        float part = 0.f;
#pragma unroll
        for (int j = 0; j < 8; ++j) {
            float v = acc[r][j] + bv[j];
            acc[r][j] = v;
            part = fmaf(v, av[j], part);
        }
        part += __shfl_xor(part, 1);    // combine the 2 col-threads of this head
        if (grow < M) {
            if (f_out) {
                union { __half hh[8]; float4 v4; } pk;
#pragma unroll
                for (int j = 0; j < 8; ++j) pk.hh[j] = __float2half(acc[r][j]);
                *(float4*)(f_out + (size_t)grow * 128 + ct * 8) = pk.v4;
            }
            if ((ct & 1) == 0)
                e_out[(size_t)grow * 8 + h] = part;
        }
    }
}

// ---------------------------------------------------------------------------
// CSR build
// ---------------------------------------------------------------------------
__global__ void degree_kernel(const int* __restrict__ dst_idx,
                              int* __restrict__ deg, int ne) {
    int e = blockIdx.x * 256 + threadIdx.x;
    if (e < ne) atomicAdd(&deg[dst_idx[e]], 1);
}

__global__ void scan1(const int* __restrict__ deg, int* __restrict__ excl,
                      int* __restrict__ bsum, int n) {
    __shared__ int tmp[256];
    int t = threadIdx.x;
    int i = blockIdx.x * 256 + t;
    int v = (i < n) ? deg[i] : 0;
    tmp[t] = v;
    __syncthreads();
    for (int off = 1; off < 256; off <<= 1) {
        int x = 0;
        if (t >= off) x = tmp[t - off];
        __syncthreads();
        tmp[t] += x;
        __syncthreads();
    }
    if (i < n) excl[i] = tmp[t] - v;
    if (t == 255) bsum[blockIdx.x] = tmp[255];
}

__global__ void scan2(int* __restrict__ bsum, int nb) {
    __shared__ int tmp[512];
    int t = threadIdx.x;
    int v = (t < nb) ? bsum[t] : 0;
    tmp[t] = v;
    __syncthreads();
    for (int off = 1; off < 512; off <<= 1) {
        int x = 0;
        if (t >= off) x = tmp[t - off];
        __syncthreads();
        tmp[t] += x;
        __syncthreads();
    }
    if (t < nb) bsum[t] = tmp[t] - v;   // exclusive block offsets
}

__global__ void scan3(const int* __restrict__ excl, const int* __restrict__ bsum,
                      int* __restrict__ roff, int n) {
    int i = blockIdx.x * 256 + threadIdx.x;
    if (i < n) roff[i] = excl[i] + bsum[blockIdx.x];
}

// Phase A: only the unavoidable 4B scatter — CSR position -> edge id.
__global__ void perm_kernel(const int* __restrict__ dst_idx,
                            const int* __restrict__ roff, int* __restrict__ cur,
                            int* __restrict__ pos2edge, int ne) {
    int e = blockIdx.x * 256 + threadIdx.x;
    if (e < ne) {
        int d = dst_idx[e];
        int p = roff[d] + atomicAdd(&cur[d], 1);
        pos2edge[p] = e;
    }
}

// Phase B: iterate CSR positions sequentially; all heavy writes coalesced.
// csr[p] = src node; wE[p][h] = exp(leaky(el[src][h] + er[dst][h])).
__global__ void weight_kernel(const int* __restrict__ pos2edge,
                              const int* __restrict__ src_idx,
                              const int* __restrict__ dst_idx,
                              const float* __restrict__ el,
                              const float* __restrict__ er,
                              int* __restrict__ csr,
                              __hip_bfloat16* __restrict__ wE, int ne) {
    int p = blockIdx.x * 256 + threadIdx.x;
    if (p >= ne) return;
    int e = pos2edge[p];
    int s = src_idx[e];
    int d = dst_idx[e];
    csr[p] = s;

    float4 l0 = *(const float4*)(el + (size_t)s * 8);
    float4 l1 = *(const float4*)(el + (size_t)s * 8 + 4);
    float4 r0 = *(const float4*)(er + (size_t)d * 8);
    float4 r1 = *(const float4*)(er + (size_t)d * 8 + 4);
    float ev[8] = {l0.x + r0.x, l0.y + r0.y, l0.z + r0.z, l0.w + r0.w,
                   l1.x + r1.x, l1.y + r1.y, l1.z + r1.z, l1.w + r1.w};
    union { __hip_bfloat16 wh[8]; float4 v4; } pk;
#pragma unroll
    for (int h = 0; h < 8; ++h) {
        float x = ev[h];
        x = (x < 0.f) ? SLOPE * x : x;
        pk.wh[h] = __float2bfloat16(__expf(x));
    }
    *(float4*)(wE + (size_t)p * 8) = pk.v4;   // coalesced 16B stream
}

// ---------------------------------------------------------------------------
// Aggregation: one wave per dst node. lane owns dims 2l,2l+1; head = l>>3.
// out[dst] = sum_e w_e * fs[src_e] / sum_e w_e   (== edge_softmax + u_mul_e + sum)
// 4-way unrolled: 4 independent fs gathers in flight per wave.
// ---------------------------------------------------------------------------
__global__ __launch_bounds__(256) void agg_kernel(
    const __half* __restrict__ fs, const __hip_bfloat16* __restrict__ wE,
    const int* __restrict__ roff, const int* __restrict__ deg,
    const int* __restrict__ csr, float* __restrict__ out, int n)
{
    int node = blockIdx.x * 4 + (threadIdx.x >> 6);
    if (node >= n) return;
    int lane = threadIdx.x & 63;
    int h = lane >> 3;
    int start = roff[node];
    int d = deg[node];

    float accx = 0.f, accy = 0.f, wsum = 0.f;
    int i = 0;
    for (; i + 4 <= d; i += 4) {
        int s0 = csr[start + i + 0];
        int s1 = csr[start + i + 1];
        int s2 = csr[start + i + 2];
        int s3 = csr[start + i + 3];
        float w0 = __bfloat162float(wE[(size_t)(start + i + 0) * 8 + h]);
        float w1 = __bfloat162float(wE[(size_t)(start + i + 1) * 8 + h]);
        float w2 = __bfloat162float(wE[(size_t)(start + i + 2) * 8 + h]);
        float w3 = __bfloat162float(wE[(size_t)(start + i + 3) * 8 + h]);
        __half2 f0 = *(const __half2*)(fs + (size_t)s0 * 128 + 2 * lane);
        __half2 f1 = *(const __half2*)(fs + (size_t)s1 * 128 + 2 * lane);
        __half2 f2 = *(const __half2*)(fs + (size_t)s2 * 128 + 2 * lane);
        __half2 f3 = *(const __half2*)(fs + (size_t)s3 * 128 + 2 * lane);
        float2 a0 = __half22float2(f0);
        float2 a1 = __half22float2(f1);
        float2 a2 = __half22float2(f2);
        float2 a3 = __half22float2(f3);
        accx = fmaf(w0, a0.x, accx); accy = fmaf(w0, a0.y, accy);
        accx = fmaf(w1, a1.x, accx); accy = fmaf(w1, a1.y, accy);
        accx = fmaf(w2, a2.x, accx); accy = fmaf(w2, a2.y, accy);
        accx = fmaf(w3, a3.x, accx); accy = fmaf(w3, a3.y, accy);
        wsum += (w0 + w1) + (w2 + w3);
    }
    for (; i < d; ++i) {
        int s = csr[start + i];
        float wgt = __bfloat162float(wE[(size_t)(start + i) * 8 + h]);
        __half2 f2v = *(const __half2*)(fs + (size_t)s * 128 + 2 * lane);
        float2 ff = __half22float2(f2v);
        accx = fmaf(wgt, ff.x, accx);
        accy = fmaf(wgt, ff.y, accy);
        wsum += wgt;
    }
    float inv = (d > 0) ? 1.0f / wsum : 0.f;
    float2 o;
    o.x = accx * inv;
    o.y = accy * inv;
    *(float2*)(out + (size_t)node * 128 + 2 * lane) = o;
}

// ---------------------------------------------------------------------------
extern "C" void kernel_launch(void* const* d_in, const int* in_sizes, int n_in,
                              void* d_out, int out_size, void* d_ws, size_t ws_size,
                              hipStream_t stream) {
    const float* feat_src = (const float*)d_in[0];
    const float* feat_dst = (const float*)d_in[1];
    const float* feat_rel = (const float*)d_in[2];
    const float* W_src    = (const float*)d_in[3];
    const float* b_src    = (const float*)d_in[4];
    const float* W_dst    = (const float*)d_in[5];
    const float* b_dst    = (const float*)d_in[6];
    const float* W_rel    = (const float*)d_in[7];
    const float* b_rel    = (const float*)d_in[8];
    const int*   src_idx  = (const int*)d_in[9];
    const int*   dst_idx  = (const int*)d_in[10];
    float* out = (float*)d_out;

    int n_src = in_sizes[0] / 128;
    int n_dst = in_sizes[1] / 128;
    int ne    = in_sizes[9];

    char* w = (char*)d_ws;
    auto alloc = [&](size_t b) { char* p = w; w += (b + 255) & ~(size_t)255; return p; };
    __half* fs   = (__half*)alloc((size_t)n_src * 128 * 2);
    float*  el   = (float*)alloc((size_t)n_src * 8 * 4);
    float*  er   = (float*)alloc((size_t)n_dst * 8 * 4);
    float*  attn = (float*)alloc(256 * 4);
    int*    deg  = (int*)alloc((size_t)n_dst * 4);
    int*    cur  = (int*)alloc((size_t)n_dst * 4);
    int*    excl = (int*)alloc((size_t)n_dst * 4);
    int*    bsum = (int*)alloc(512 * 4);
    int*    roff = (int*)alloc((size_t)n_dst * 4);
    int*    csr  = (int*)alloc((size_t)ne * 4);
    int*    p2e  = (int*)alloc((size_t)ne * 4);
    __hip_bfloat16* wE = (__hip_bfloat16*)alloc((size_t)ne * 8 * 2);

    attn_kernel<<<1, 256, 0, stream>>>(feat_rel, W_rel, b_rel, attn);

    gemm_el_kernel<<<(n_src + 63) / 64, 256, 0, stream>>>(
        feat_src, W_src, b_src, attn, 0, fs, el, n_src);
    gemm_el_kernel<<<(n_dst + 63) / 64, 256, 0, stream>>>(
        feat_dst, W_dst, b_dst, attn, 16, (__half*)nullptr, er, n_dst);

    hipMemsetAsync(deg, 0, (size_t)n_dst * 4, stream);
    hipMemsetAsync(cur, 0, (size_t)n_dst * 4, stream);

    degree_kernel<<<(ne + 255) / 256, 256, 0, stream>>>(dst_idx, deg, ne);
    int nb = (n_dst + 255) / 256;
    scan1<<<nb, 256, 0, stream>>>(deg, excl, bsum, n_dst);
    scan2<<<1, 512, 0, stream>>>(bsum, nb);
    scan3<<<nb, 256, 0, stream>>>(excl, bsum, roff, n_dst);

    perm_kernel<<<(ne + 255) / 256, 256, 0, stream>>>(dst_idx, roff, cur, p2e, ne);
    weight_kernel<<<(ne + 255) / 256, 256, 0, stream>>>(
        p2e, src_idx, dst_idx, el, er, csr, wE, ne);

    agg_kernel<<<(n_dst + 3) / 4, 256, 0, stream>>>(fs, wE, roff, deg, csr, out, n_dst);
}

// Round 5
// 465.563 us; speedup vs baseline: 1.2117x; 1.2117x over previous
//
#include <hip/hip_runtime.h>
#include <hip/hip_fp16.h>
#include <hip/hip_bf16.h>

#define SLOPE 0.2f
#define EPB 4096   // edges per block in part_kernel (16/thread)

typedef float vf2 __attribute__((ext_vector_type(2)));

// ---------------------------------------------------------------------------
// attn = feat_rel @ W_rel + b_rel   (1 block, 256 threads, one col each)
// ---------------------------------------------------------------------------
__global__ void attn_kernel(const float* __restrict__ feat_rel,
                            const float* __restrict__ W_rel,
                            const float* __restrict__ b_rel,
                            float* __restrict__ attn) {
    int j = threadIdx.x;            // 0..255
    float acc = b_rel[j];
    for (int d = 0; d < 128; ++d)
        acc = fmaf(feat_rel[d], W_rel[d * 256 + j], acc);
    attn[j] = acc;
}

// ---------------------------------------------------------------------------
// Fused GEMM + per-head attention-scalar epilogue.
// ---------------------------------------------------------------------------
__global__ __launch_bounds__(256) void gemm_el_kernel(
    const float* __restrict__ feat, const float* __restrict__ W,
    const float* __restrict__ bias, const float* __restrict__ attn,
    int attn_off, __half* __restrict__ f_out, float* __restrict__ e_out,
    int M)
{
    __shared__ float sA[64][68];    // [k][row], padded stride 68
    __shared__ float sW[64][128];   // [k][col]

    int t  = threadIdx.x;
    int rt = t >> 4;
    int ct = t & 15;
    int row0 = blockIdx.x * 64;

    float acc[4][8];
#pragma unroll
    for (int r = 0; r < 4; ++r)
#pragma unroll
        for (int j = 0; j < 8; ++j) acc[r][j] = 0.f;

    for (int kc = 0; kc < 2; ++kc) {
        int k0 = kc * 64;
        {
            int rr = t >> 4;
            int k4 = t & 15;
#pragma unroll
            for (int i = 0; i < 4; ++i) {
                int row = rr + i * 16;
                int grow = row0 + row;
                float4 v = {0.f, 0.f, 0.f, 0.f};
                if (grow < M)
                    v = *(const float4*)(feat + (size_t)grow * 128 + k0 + k4 * 4);
                sA[k4 * 4 + 0][row] = v.x;
                sA[k4 * 4 + 1][row] = v.y;
                sA[k4 * 4 + 2][row] = v.z;
                sA[k4 * 4 + 3][row] = v.w;
            }
        }
        {
#pragma unroll
            for (int i = 0; i < 8; ++i) {
                int idx = t + i * 256;
                int k = idx >> 5, j4 = idx & 31;
                *(float4*)&sW[k][j4 * 4] =
                    *(const float4*)(W + (size_t)(k0 + k) * 128 + j4 * 4);
            }
        }
        __syncthreads();
#pragma unroll 4
        for (int kk = 0; kk < 64; ++kk) {
            float4 a  = *(const float4*)&sA[kk][rt * 4];
            float4 b0 = *(const float4*)&sW[kk][ct * 8];
            float4 b1 = *(const float4*)&sW[kk][ct * 8 + 4];
            float av[4]  = {a.x, a.y, a.z, a.w};
            float bv[8]  = {b0.x, b0.y, b0.z, b0.w, b1.x, b1.y, b1.z, b1.w};
#pragma unroll
            for (int r = 0; r < 4; ++r)
#pragma unroll
                for (int j = 0; j < 8; ++j)
                    acc[r][j] = fmaf(av[r], bv[j], acc[r][j]);
        }
        __syncthreads();
    }

    int h    = ct >> 1;
    int doff = (ct & 1) * 8;
    float bv[8], av[8];
#pragma unroll
    for (int j = 0; j < 8; ++j) {
        bv[j] = bias[ct * 8 + j];
        av[j] = attn[h * 32 + attn_off + doff + j];
    }
#pragma unroll
    for (int r = 0; r < 4; ++r) {
        int grow = row0 + rt * 4 + r;
        float part = 0.f;
#pragma unroll
        for (int j = 0; j < 8; ++j) {
            float v = acc[r][j] + bv[j];
            acc[r][j] = v;
            part = fmaf(v, av[j], part);
        }
        part += __shfl_xor(part, 1);
        if (grow < M) {
            if (f_out) {
                union { __half hh[8]; float4 v4; } pk;
#pragma unroll
                for (int j = 0; j < 8; ++j) pk.hh[j] = __float2half(acc[r][j]);
                *(float4*)(f_out + (size_t)grow * 128 + ct * 8) = pk.v4;
            }
            if ((ct & 1) == 0)
                e_out[(size_t)grow * 8 + h] = part;
        }
    }
}

// ---------------------------------------------------------------------------
// CSR build: degree + scan
// ---------------------------------------------------------------------------
__global__ void degree_kernel(const int* __restrict__ dst_idx,
                              int* __restrict__ deg, int ne) {
    int e = blockIdx.x * 256 + threadIdx.x;
    if (e < ne) atomicAdd(&deg[dst_idx[e]], 1);
}

__global__ void scan1(const int* __restrict__ deg, int* __restrict__ excl,
                      int* __restrict__ bsum, int n) {
    __shared__ int tmp[256];
    int t = threadIdx.x;
    int i = blockIdx.x * 256 + t;
    int v = (i < n) ? deg[i] : 0;
    tmp[t] = v;
    __syncthreads();
    for (int off = 1; off < 256; off <<= 1) {
        int x = 0;
        if (t >= off) x = tmp[t - off];
        __syncthreads();
        tmp[t] += x;
        __syncthreads();
    }
    if (i < n) excl[i] = tmp[t] - v;
    if (t == 255) bsum[blockIdx.x] = tmp[255];
}

__global__ void scan2(int* __restrict__ bsum, int nb) {
    __shared__ int tmp[512];
    int t = threadIdx.x;
    int v = (t < nb) ? bsum[t] : 0;
    tmp[t] = v;
    __syncthreads();
    for (int off = 1; off < 512; off <<= 1) {
        int x = 0;
        if (t >= off) x = tmp[t - off];
        __syncthreads();
        tmp[t] += x;
        __syncthreads();
    }
    if (t < nb) bsum[t] = tmp[t] - v;
}

__global__ void scan3(const int* __restrict__ excl, const int* __restrict__ bsum,
                      int* __restrict__ roff, int n) {
    int i = blockIdx.x * 256 + threadIdx.x;
    if (i < n) roff[i] = excl[i] + bsum[blockIdx.x];
}

// bucket b (128 dst nodes) gets CSR position range [roff[b*128], roff[(b+1)*128])
__global__ void initcur_kernel(const int* __restrict__ roff,
                               int* __restrict__ bcur, int nbuck) {
    int b = blockIdx.x * 256 + threadIdx.x;
    if (b < nbuck) bcur[b] = roff[(size_t)b << 7];
}

// ---------------------------------------------------------------------------
// Pass 1: LDS-histogram radix partition of edges into dst-buckets.
// Per-(block,bucket) writes are short contiguous runs -> low line amplification.
// ---------------------------------------------------------------------------
__global__ __launch_bounds__(256) void part_kernel(
    const int* __restrict__ src_idx, const int* __restrict__ dst_idx,
    int* __restrict__ bcur, int2* __restrict__ part, int ne)
{
    __shared__ int hist[1024];
    __shared__ int base[1024];
    int tid = threadIdx.x;
    for (int i = tid; i < 1024; i += 256) hist[i] = 0;
    int e0 = blockIdx.x * EPB;
    int myS[16], myD[16];
    __syncthreads();
#pragma unroll
    for (int i = 0; i < 16; ++i) {
        int e = e0 + i * 256 + tid;
        if (e < ne) {
            myS[i] = src_idx[e];
            myD[i] = dst_idx[e];
            atomicAdd(&hist[myD[i] >> 7], 1);
        } else myD[i] = -1;
    }
    __syncthreads();
    for (int b = tid; b < 1024; b += 256) {
        int c = hist[b];
        if (c > 0) {
            base[b] = atomicAdd(&bcur[b], c);
            hist[b] = 0;
        }
    }
    __syncthreads();
#pragma unroll
    for (int i = 0; i < 16; ++i) {
        if (myD[i] >= 0) {
            int b = myD[i] >> 7;
            int slot = base[b] + atomicAdd(&hist[b], 1);
            part[slot] = make_int2(myS[i], myD[i]);
        }
    }
}

// ---------------------------------------------------------------------------
// Pass 2: one block OWNS one bucket's CSR position window.
// Fine placement via LDS per-node counters; csr/wE writes stay in this
// block's XCD L2 until lines are fully assembled -> 1x writebacks.
// ---------------------------------------------------------------------------
__global__ __launch_bounds__(256) void place_kernel(
    const int2* __restrict__ part, const int* __restrict__ roff,
    const float* __restrict__ el, const float* __restrict__ er,
    int* __restrict__ csr, __hip_bfloat16* __restrict__ wE,
    int n_dst, int ne)
{
    int b = blockIdx.x;
    int node0 = b << 7;
    int tid = threadIdx.x;
    __shared__ int curs[128];
    __shared__ float ers[128 * 8];
    if (tid < 128) curs[tid] = 0;
    int nend = node0 + 128; if (nend > n_dst) nend = n_dst;
    for (int i = tid; i < (nend - node0) * 8; i += 256)
        ers[i] = er[(size_t)node0 * 8 + i];
    int pstart = roff[node0];
    int pend = (nend >= n_dst) ? ne : roff[nend];
    __syncthreads();

    for (int pi = pstart + tid; pi < pend; pi += 256) {
        int2 sd = part[pi];                 // coalesced
        int s = sd.x, d = sd.y;
        int fine = atomicAdd(&curs[d & 127], 1);
        int p = roff[d] + fine;             // roff gather: 512B window, L1-hot
        csr[p] = s;
        float4 l0 = *(const float4*)(el + (size_t)s * 8);
        float4 l1 = *(const float4*)(el + (size_t)s * 8 + 4);
        const float* e8 = &ers[(d & 127) * 8];
        float ev[8] = {l0.x + e8[0], l0.y + e8[1], l0.z + e8[2], l0.w + e8[3],
                       l1.x + e8[4], l1.y + e8[5], l1.z + e8[6], l1.w + e8[7]};
        union { __hip_bfloat16 wh[8]; float4 v4; } pk;
#pragma unroll
        for (int h = 0; h < 8; ++h) {
            float x = ev[h];
            x = (x < 0.f) ? SLOPE * x : x;
            pk.wh[h] = __float2bfloat16(__expf(x));
        }
        *(float4*)(wE + (size_t)p * 8) = pk.v4;
    }
}

// ---------------------------------------------------------------------------
// Aggregation: one wave per dst node. lane owns dims 2l,2l+1; head = l>>3.
// 8-way unrolled gathers; NT loads on once-read csr/wE streams; NT store out.
// ---------------------------------------------------------------------------
__global__ __launch_bounds__(256) void agg_kernel(
    const __half* __restrict__ fs, const __hip_bfloat16* __restrict__ wE,
    const int* __restrict__ roff, const int* __restrict__ deg,
    const int* __restrict__ csr, float* __restrict__ out, int n)
{
    int node = blockIdx.x * 4 + (threadIdx.x >> 6);
    if (node >= n) return;
    int lane = threadIdx.x & 63;
    int h = lane >> 3;
    int start = roff[node];
    int d = deg[node];
    const unsigned short* wEu = (const unsigned short*)wE;

    float accx = 0.f, accy = 0.f, wsum = 0.f;
    int i = 0;
    for (; i + 8 <= d; i += 8) {
        int s[8]; float w[8]; float2 a[8];
#pragma unroll
        for (int j = 0; j < 8; ++j)
            s[j] = __builtin_nontemporal_load(csr + start + i + j);
#pragma unroll
        for (int j = 0; j < 8; ++j) {
            unsigned short u =
                __builtin_nontemporal_load(wEu + (size_t)(start + i + j) * 8 + h);
            w[j] = __uint_as_float(((unsigned)u) << 16);
        }
#pragma unroll
        for (int j = 0; j < 8; ++j)
            a[j] = __half22float2(*(const __half2*)(fs + (size_t)s[j] * 128 + 2 * lane));
#pragma unroll
        for (int j = 0; j < 8; ++j) {
            accx = fmaf(w[j], a[j].x, accx);
            accy = fmaf(w[j], a[j].y, accy);
            wsum += w[j];
        }
    }
    for (; i + 2 <= d; i += 2) {
        int s0 = __builtin_nontemporal_load(csr + start + i + 0);
        int s1 = __builtin_nontemporal_load(csr + start + i + 1);
        unsigned short u0 = __builtin_nontemporal_load(wEu + (size_t)(start + i + 0) * 8 + h);
        unsigned short u1 = __builtin_nontemporal_load(wEu + (size_t)(start + i + 1) * 8 + h);
        float w0 = __uint_as_float(((unsigned)u0) << 16);
        float w1 = __uint_as_float(((unsigned)u1) << 16);
        float2 a0 = __half22float2(*(const __half2*)(fs + (size_t)s0 * 128 + 2 * lane));
        float2 a1 = __half22float2(*(const __half2*)(fs + (size_t)s1 * 128 + 2 * lane));
        accx = fmaf(w0, a0.x, accx); accy = fmaf(w0, a0.y, accy);
        accx = fmaf(w1, a1.x, accx); accy = fmaf(w1, a1.y, accy);
        wsum += w0 + w1;
    }
    for (; i < d; ++i) {
        int s = __builtin_nontemporal_load(csr + start + i);
        unsigned short u = __builtin_nontemporal_load(wEu + (size_t)(start + i) * 8 + h);
        float wgt = __uint_as_float(((unsigned)u) << 16);
        float2 ff = __half22float2(*(const __half2*)(fs + (size_t)s * 128 + 2 * lane));
        accx = fmaf(wgt, ff.x, accx);
        accy = fmaf(wgt, ff.y, accy);
        wsum += wgt;
    }
    float inv = (d > 0) ? 1.0f / wsum : 0.f;
    vf2 o;
    o.x = accx * inv;
    o.y = accy * inv;
    __builtin_nontemporal_store(o, (vf2*)(out + (size_t)node * 128 + 2 * lane));
}

// ---------------------------------------------------------------------------
extern "C" void kernel_launch(void* const* d_in, const int* in_sizes, int n_in,
                              void* d_out, int out_size, void* d_ws, size_t ws_size,
                              hipStream_t stream) {
    const float* feat_src = (const float*)d_in[0];
    const float* feat_dst = (const float*)d_in[1];
    const float* feat_rel = (const float*)d_in[2];
    const float* W_src    = (const float*)d_in[3];
    const float* b_src    = (const float*)d_in[4];
    const float* W_dst    = (const float*)d_in[5];
    const float* b_dst    = (const float*)d_in[6];
    const float* W_rel    = (const float*)d_in[7];
    const float* b_rel    = (const float*)d_in[8];
    const int*   src_idx  = (const int*)d_in[9];
    const int*   dst_idx  = (const int*)d_in[10];
    float* out = (float*)d_out;

    int n_src = in_sizes[0] / 128;
    int n_dst = in_sizes[1] / 128;
    int ne    = in_sizes[9];
    int nbuck = (n_dst + 127) >> 7;

    char* w = (char*)d_ws;
    auto alloc = [&](size_t b) { char* p = w; w += (b + 255) & ~(size_t)255; return p; };
    __half* fs   = (__half*)alloc((size_t)n_src * 128 * 2);
    float*  el   = (float*)alloc((size_t)n_src * 8 * 4);
    float*  er   = (float*)alloc((size_t)n_dst * 8 * 4);
    float*  attn = (float*)alloc(256 * 4);
    int*    deg  = (int*)alloc((size_t)n_dst * 4);
    int*    excl = (int*)alloc((size_t)n_dst * 4);
    int*    bsum = (int*)alloc(512 * 4);
    int*    roff = (int*)alloc((size_t)n_dst * 4);
    int*    bcur = (int*)alloc(1024 * 4);
    int*    csr  = (int*)alloc((size_t)ne * 4);
    int2*   part = (int2*)alloc((size_t)ne * 8);
    __hip_bfloat16* wE = (__hip_bfloat16*)alloc((size_t)ne * 8 * 2);

    attn_kernel<<<1, 256, 0, stream>>>(feat_rel, W_rel, b_rel, attn);

    gemm_el_kernel<<<(n_src + 63) / 64, 256, 0, stream>>>(
        feat_src, W_src, b_src, attn, 0, fs, el, n_src);
    gemm_el_kernel<<<(n_dst + 63) / 64, 256, 0, stream>>>(
        feat_dst, W_dst, b_dst, attn, 16, (__half*)nullptr, er, n_dst);

    (void)hipMemsetAsync(deg, 0, (size_t)n_dst * 4, stream);

    degree_kernel<<<(ne + 255) / 256, 256, 0, stream>>>(dst_idx, deg, ne);
    int nb = (n_dst + 255) / 256;
    scan1<<<nb, 256, 0, stream>>>(deg, excl, bsum, n_dst);
    scan2<<<1, 512, 0, stream>>>(bsum, nb);
    scan3<<<nb, 256, 0, stream>>>(excl, bsum, roff, n_dst);

    initcur_kernel<<<(nbuck + 255) / 256, 256, 0, stream>>>(roff, bcur, nbuck);
    part_kernel<<<(ne + EPB - 1) / EPB, 256, 0, stream>>>(src_idx, dst_idx, bcur, part, ne);
    place_kernel<<<nbuck, 256, 0, stream>>>(part, roff, el, er, csr, wE, n_dst, ne);

    agg_kernel<<<(n_dst + 3) / 4, 256, 0, stream>>>(fs, wE, roff, deg, csr, out, n_dst);
}

// Round 6
// 444.381 us; speedup vs baseline: 1.2695x; 1.0477x over previous
//
#include <hip/hip_runtime.h>
#include <hip/hip_fp16.h>
#include <hip/hip_bf16.h>

#define SLOPE 0.2f
#define EPB 4096   // edges per block in part_kernel (16/thread)
#define LDA 136    // padded LDS row (bf16 elems): 272B stride -> 2-way-free banks

typedef float vf2 __attribute__((ext_vector_type(2)));
typedef short bf16x8 __attribute__((ext_vector_type(8)));
typedef float f32x4 __attribute__((ext_vector_type(4)));

__device__ __forceinline__ unsigned short f2bf(float x) {
    unsigned u = __float_as_uint(x);
    u += 0x7FFFu + ((u >> 16) & 1u);     // RNE
    return (unsigned short)(u >> 16);
}

// ---------------------------------------------------------------------------
// attn = feat_rel @ W_rel + b_rel   (1 block, 256 threads, one col each)
// ---------------------------------------------------------------------------
__global__ void attn_kernel(const float* __restrict__ feat_rel,
                            const float* __restrict__ W_rel,
                            const float* __restrict__ b_rel,
                            float* __restrict__ attn) {
    int j = threadIdx.x;            // 0..255
    float acc = b_rel[j];
    for (int d = 0; d < 128; ++d)
        acc = fmaf(feat_rel[d], W_rel[d * 256 + j], acc);
    attn[j] = acc;
}

// W (128x128 row-major [k][n], fp32) -> Wt (bf16, [n][k])
__global__ void wt_kernel(const float* __restrict__ W,
                          unsigned short* __restrict__ Wt) {
    int t = blockIdx.x * 256 + threadIdx.x;   // 16384
    int n = t >> 7, k = t & 127;
    Wt[n * 128 + k] = f2bf(W[k * 128 + n]);
}

// ---------------------------------------------------------------------------
// MFMA GEMM: f = feat @ W + b (64 rows x 128 cols per block), fused epilogue:
// fs fp16 store + el[row][h] = sum_d f*attn. 4 waves; wave wv owns cols wv*32..+31.
// mfma_f32_16x16x32_bf16: A[m=lane&15][k=quad*8+j]; B[k][n=lane&15];
// C/D col=lane&15, row=quad*4+reg (m89-verified).
// ---------------------------------------------------------------------------
__global__ __launch_bounds__(256) void gemm_mfma_kernel(
    const float* __restrict__ feat, const unsigned short* __restrict__ Wt,
    const float* __restrict__ bias, const float* __restrict__ attn,
    int attn_off, __half* __restrict__ f_out, float* __restrict__ e_out,
    int M)
{
    __shared__ unsigned short sA[64 * LDA];    // [row][k] bf16
    __shared__ unsigned short sB[128 * LDA];   // [n][k]  bf16

    int t = threadIdx.x;
    int row0 = blockIdx.x * 64;

    // stage A: 64x128 fp32 -> bf16; 2048 float4s / 256 thr = 8 each
#pragma unroll
    for (int i = 0; i < 8; ++i) {
        int idx = t + i * 256;
        int row = idx >> 5, k4 = idx & 31;
        int grow = row0 + row;
        float4 v = {0.f, 0.f, 0.f, 0.f};
        if (grow < M) v = *(const float4*)(feat + (size_t)grow * 128 + k4 * 4);
        ushort4 b;
        b.x = f2bf(v.x); b.y = f2bf(v.y); b.z = f2bf(v.z); b.w = f2bf(v.w);
        *(ushort4*)&sA[row * LDA + k4 * 4] = b;   // 8B aligned (272B rows)
    }
    // stage B: Wt bf16 128x128 -> padded LDS; 2048 16B chunks / 256 = 8 each
#pragma unroll
    for (int i = 0; i < 8; ++i) {
        int idx = t + i * 256;
        int n = idx >> 4, koff = (idx & 15) * 8;
        *(uint4*)&sB[n * LDA + koff] = *(const uint4*)&Wt[n * 128 + koff];
    }
    __syncthreads();

    int wv = t >> 6, lane = t & 63;
    int m = lane & 15, quad = lane >> 4;
    int n0 = wv * 32;

    f32x4 acc[2][4];
#pragma unroll
    for (int ct = 0; ct < 2; ++ct)
#pragma unroll
        for (int rt = 0; rt < 4; ++rt) acc[ct][rt] = (f32x4){0.f, 0.f, 0.f, 0.f};

#pragma unroll
    for (int ks = 0; ks < 4; ++ks) {
        bf16x8 a[4], b[2];
#pragma unroll
        for (int rt = 0; rt < 4; ++rt)
            a[rt] = *(const bf16x8*)&sA[(rt * 16 + m) * LDA + ks * 32 + quad * 8];
#pragma unroll
        for (int ct = 0; ct < 2; ++ct)
            b[ct] = *(const bf16x8*)&sB[(n0 + ct * 16 + m) * LDA + ks * 32 + quad * 8];
#pragma unroll
        for (int ct = 0; ct < 2; ++ct)
#pragma unroll
            for (int rt = 0; rt < 4; ++rt)
                acc[ct][rt] = __builtin_amdgcn_mfma_f32_16x16x32_bf16(
                    a[rt], b[ct], acc[ct][rt], 0, 0, 0);
    }

    // epilogue
#pragma unroll
    for (int ct = 0; ct < 2; ++ct) {
        int gcol = n0 + ct * 16 + m;
        int h = gcol >> 4;
        float bias_v = bias[gcol];
        float attn_v = attn[h * 32 + attn_off + (gcol & 15)];
#pragma unroll
        for (int rt = 0; rt < 4; ++rt) {
            f32x4 c = acc[ct][rt];
#pragma unroll
            for (int r = 0; r < 4; ++r) {
                float v = c[r] + bias_v;
                int grow = row0 + rt * 16 + quad * 4 + r;
                float p = v * attn_v;
                p += __shfl_xor(p, 1);
                p += __shfl_xor(p, 2);
                p += __shfl_xor(p, 4);
                p += __shfl_xor(p, 8);
                if (grow < M) {
                    if (f_out) f_out[(size_t)grow * 128 + gcol] = __float2half(v);
                    if (m == 0) e_out[(size_t)grow * 8 + h] = p;
                }
            }
        }
    }
}

// ---------------------------------------------------------------------------
// CSR build: degree + scan
// ---------------------------------------------------------------------------
__global__ void degree_kernel(const int* __restrict__ dst_idx,
                              int* __restrict__ deg, int ne) {
    int e = blockIdx.x * 256 + threadIdx.x;
    if (e < ne) atomicAdd(&deg[dst_idx[e]], 1);
}

__global__ void scan1(const int* __restrict__ deg, int* __restrict__ excl,
                      int* __restrict__ bsum, int n) {
    __shared__ int tmp[256];
    int t = threadIdx.x;
    int i = blockIdx.x * 256 + t;
    int v = (i < n) ? deg[i] : 0;
    tmp[t] = v;
    __syncthreads();
    for (int off = 1; off < 256; off <<= 1) {
        int x = 0;
        if (t >= off) x = tmp[t - off];
        __syncthreads();
        tmp[t] += x;
        __syncthreads();
    }
    if (i < n) excl[i] = tmp[t] - v;
    if (t == 255) bsum[blockIdx.x] = tmp[255];
}

__global__ void scan2(int* __restrict__ bsum, int nb) {
    __shared__ int tmp[512];
    int t = threadIdx.x;
    int v = (t < nb) ? bsum[t] : 0;
    tmp[t] = v;
    __syncthreads();
    for (int off = 1; off < 512; off <<= 1) {
        int x = 0;
        if (t >= off) x = tmp[t - off];
        __syncthreads();
        tmp[t] += x;
        __syncthreads();
    }
    if (t < nb) bsum[t] = tmp[t] - v;
}

__global__ void scan3(const int* __restrict__ excl, const int* __restrict__ bsum,
                      int* __restrict__ roff, int n) {
    int i = blockIdx.x * 256 + threadIdx.x;
    if (i < n) roff[i] = excl[i] + bsum[blockIdx.x];
}

// bucket b (128 dst nodes) gets CSR position range [roff[b*128], roff[(b+1)*128])
__global__ void initcur_kernel(const int* __restrict__ roff,
                               int* __restrict__ bcur, int nbuck) {
    int b = blockIdx.x * 256 + threadIdx.x;
    if (b < nbuck) bcur[b] = roff[(size_t)b << 7];
}

// ---------------------------------------------------------------------------
// Pass 1: LDS-histogram radix partition of edges into dst-buckets.
// ---------------------------------------------------------------------------
__global__ __launch_bounds__(256) void part_kernel(
    const int* __restrict__ src_idx, const int* __restrict__ dst_idx,
    int* __restrict__ bcur, int2* __restrict__ part, int ne)
{
    __shared__ int hist[1024];
    __shared__ int base[1024];
    int tid = threadIdx.x;
    for (int i = tid; i < 1024; i += 256) hist[i] = 0;
    int e0 = blockIdx.x * EPB;
    int myS[16], myD[16];
    __syncthreads();
#pragma unroll
    for (int i = 0; i < 16; ++i) {
        int e = e0 + i * 256 + tid;
        if (e < ne) {
            myS[i] = src_idx[e];
            myD[i] = dst_idx[e];
            atomicAdd(&hist[myD[i] >> 7], 1);
        } else myD[i] = -1;
    }
    __syncthreads();
    for (int b = tid; b < 1024; b += 256) {
        int c = hist[b];
        if (c > 0) {
            base[b] = atomicAdd(&bcur[b], c);
            hist[b] = 0;
        }
    }
    __syncthreads();
#pragma unroll
    for (int i = 0; i < 16; ++i) {
        if (myD[i] >= 0) {
            int b = myD[i] >> 7;
            int slot = base[b] + atomicAdd(&hist[b], 1);
            part[slot] = make_int2(myS[i], myD[i]);
        }
    }
}

// ---------------------------------------------------------------------------
// Pass 2: one block OWNS one bucket's CSR position window.
// ---------------------------------------------------------------------------
__global__ __launch_bounds__(256) void place_kernel(
    const int2* __restrict__ part, const int* __restrict__ roff,
    const float* __restrict__ el, const float* __restrict__ er,
    int* __restrict__ csr, __hip_bfloat16* __restrict__ wE,
    int n_dst, int ne)
{
    int b = blockIdx.x;
    int node0 = b << 7;
    int tid = threadIdx.x;
    __shared__ int curs[128];
    __shared__ float ers[128 * 8];
    if (tid < 128) curs[tid] = 0;
    int nend = node0 + 128; if (nend > n_dst) nend = n_dst;
    for (int i = tid; i < (nend - node0) * 8; i += 256)
        ers[i] = er[(size_t)node0 * 8 + i];
    int pstart = roff[node0];
    int pend = (nend >= n_dst) ? ne : roff[nend];
    __syncthreads();

    for (int pi = pstart + tid; pi < pend; pi += 256) {
        int2 sd = part[pi];                 // coalesced
        int s = sd.x, d = sd.y;
        int fine = atomicAdd(&curs[d & 127], 1);
        int p = roff[d] + fine;             // roff gather: 512B window, L1-hot
        csr[p] = s;
        float4 l0 = *(const float4*)(el + (size_t)s * 8);
        float4 l1 = *(const float4*)(el + (size_t)s * 8 + 4);
        const float* e8 = &ers[(d & 127) * 8];
        float ev[8] = {l0.x + e8[0], l0.y + e8[1], l0.z + e8[2], l0.w + e8[3],
                       l1.x + e8[4], l1.y + e8[5], l1.z + e8[6], l1.w + e8[7]};
        union { __hip_bfloat16 wh[8]; float4 v4; } pk;
#pragma unroll
        for (int h = 0; h < 8; ++h) {
            float x = ev[h];
            x = (x < 0.f) ? SLOPE * x : x;
            pk.wh[h] = __float2bfloat16(__expf(x));
        }
        *(float4*)(wE + (size_t)p * 8) = pk.v4;
    }
}

// ---------------------------------------------------------------------------
// Aggregation: one wave per dst node. lane owns dims 2l,2l+1; head = l>>3.
// ---------------------------------------------------------------------------
__global__ __launch_bounds__(256) void agg_kernel(
    const __half* __restrict__ fs, const __hip_bfloat16* __restrict__ wE,
    const int* __restrict__ roff, const int* __restrict__ deg,
    const int* __restrict__ csr, float* __restrict__ out, int n)
{
    int node = blockIdx.x * 4 + (threadIdx.x >> 6);
    if (node >= n) return;
    int lane = threadIdx.x & 63;
    int h = lane >> 3;
    int start = roff[node];
    int d = deg[node];
    const unsigned short* wEu = (const unsigned short*)wE;

    float accx = 0.f, accy = 0.f, wsum = 0.f;
    int i = 0;
    for (; i + 8 <= d; i += 8) {
        int s[8]; float w[8]; float2 a[8];
#pragma unroll
        for (int j = 0; j < 8; ++j)
            s[j] = __builtin_nontemporal_load(csr + start + i + j);
#pragma unroll
        for (int j = 0; j < 8; ++j) {
            unsigned short u =
                __builtin_nontemporal_load(wEu + (size_t)(start + i + j) * 8 + h);
            w[j] = __uint_as_float(((unsigned)u) << 16);
        }
#pragma unroll
        for (int j = 0; j < 8; ++j)
            a[j] = __half22float2(*(const __half2*)(fs + (size_t)s[j] * 128 + 2 * lane));
#pragma unroll
        for (int j = 0; j < 8; ++j) {
            accx = fmaf(w[j], a[j].x, accx);
            accy = fmaf(w[j], a[j].y, accy);
            wsum += w[j];
        }
    }
    for (; i + 2 <= d; i += 2) {
        int s0 = __builtin_nontemporal_load(csr + start + i + 0);
        int s1 = __builtin_nontemporal_load(csr + start + i + 1);
        unsigned short u0 = __builtin_nontemporal_load(wEu + (size_t)(start + i + 0) * 8 + h);
        unsigned short u1 = __builtin_nontemporal_load(wEu + (size_t)(start + i + 1) * 8 + h);
        float w0 = __uint_as_float(((unsigned)u0) << 16);
        float w1 = __uint_as_float(((unsigned)u1) << 16);
        float2 a0 = __half22float2(*(const __half2*)(fs + (size_t)s0 * 128 + 2 * lane));
        float2 a1 = __half22float2(*(const __half2*)(fs + (size_t)s1 * 128 + 2 * lane));
        accx = fmaf(w0, a0.x, accx); accy = fmaf(w0, a0.y, accy);
        accx = fmaf(w1, a1.x, accx); accy = fmaf(w1, a1.y, accy);
        wsum += w0 + w1;
    }
    for (; i < d; ++i) {
        int s = __builtin_nontemporal_load(csr + start + i);
        unsigned short u = __builtin_nontemporal_load(wEu + (size_t)(start + i) * 8 + h);
        float wgt = __uint_as_float(((unsigned)u) << 16);
        float2 ff = __half22float2(*(const __half2*)(fs + (size_t)s * 128 + 2 * lane));
        accx = fmaf(wgt, ff.x, accx);
        accy = fmaf(wgt, ff.y, accy);
        wsum += wgt;
    }
    float inv = (d > 0) ? 1.0f / wsum : 0.f;
    vf2 o;
    o.x = accx * inv;
    o.y = accy * inv;
    __builtin_nontemporal_store(o, (vf2*)(out + (size_t)node * 128 + 2 * lane));
}

// ---------------------------------------------------------------------------
extern "C" void kernel_launch(void* const* d_in, const int* in_sizes, int n_in,
                              void* d_out, int out_size, void* d_ws, size_t ws_size,
                              hipStream_t stream) {
    const float* feat_src = (const float*)d_in[0];
    const float* feat_dst = (const float*)d_in[1];
    const float* feat_rel = (const float*)d_in[2];
    const float* W_src    = (const float*)d_in[3];
    const float* b_src    = (const float*)d_in[4];
    const float* W_dst    = (const float*)d_in[5];
    const float* b_dst    = (const float*)d_in[6];
    const float* W_rel    = (const float*)d_in[7];
    const float* b_rel    = (const float*)d_in[8];
    const int*   src_idx  = (const int*)d_in[9];
    const int*   dst_idx  = (const int*)d_in[10];
    float* out = (float*)d_out;

    int n_src = in_sizes[0] / 128;
    int n_dst = in_sizes[1] / 128;
    int ne    = in_sizes[9];
    int nbuck = (n_dst + 127) >> 7;

    char* w = (char*)d_ws;
    auto alloc = [&](size_t b) { char* p = w; w += (b + 255) & ~(size_t)255; return p; };
    __half* fs   = (__half*)alloc((size_t)n_src * 128 * 2);
    float*  el   = (float*)alloc((size_t)n_src * 8 * 4);
    float*  er   = (float*)alloc((size_t)n_dst * 8 * 4);
    float*  attn = (float*)alloc(256 * 4);
    unsigned short* WtS = (unsigned short*)alloc(128 * 128 * 2);
    unsigned short* WtD = (unsigned short*)alloc(128 * 128 * 2);
    int*    deg  = (int*)alloc((size_t)n_dst * 4);
    int*    excl = (int*)alloc((size_t)n_dst * 4);
    int*    bsum = (int*)alloc(512 * 4);
    int*    roff = (int*)alloc((size_t)n_dst * 4);
    int*    bcur = (int*)alloc(1024 * 4);
    int*    csr  = (int*)alloc((size_t)ne * 4);
    int2*   part = (int2*)alloc((size_t)ne * 8);
    __hip_bfloat16* wE = (__hip_bfloat16*)alloc((size_t)ne * 8 * 2);

    attn_kernel<<<1, 256, 0, stream>>>(feat_rel, W_rel, b_rel, attn);
    wt_kernel<<<64, 256, 0, stream>>>(W_src, WtS);
    wt_kernel<<<64, 256, 0, stream>>>(W_dst, WtD);

    gemm_mfma_kernel<<<(n_src + 63) / 64, 256, 0, stream>>>(
        feat_src, WtS, b_src, attn, 0, fs, el, n_src);
    gemm_mfma_kernel<<<(n_dst + 63) / 64, 256, 0, stream>>>(
        feat_dst, WtD, b_dst, attn, 16, (__half*)nullptr, er, n_dst);

    (void)hipMemsetAsync(deg, 0, (size_t)n_dst * 4, stream);

    degree_kernel<<<(ne + 255) / 256, 256, 0, stream>>>(dst_idx, deg, ne);
    int nb = (n_dst + 255) / 256;
    scan1<<<nb, 256, 0, stream>>>(deg, excl, bsum, n_dst);
    scan2<<<1, 512, 0, stream>>>(bsum, nb);
    scan3<<<nb, 256, 0, stream>>>(excl, bsum, roff, n_dst);

    initcur_kernel<<<(nbuck + 255) / 256, 256, 0, stream>>>(roff, bcur, nbuck);
    part_kernel<<<(ne + EPB - 1) / EPB, 256, 0, stream>>>(src_idx, dst_idx, bcur, part, ne);
    place_kernel<<<nbuck, 256, 0, stream>>>(part, roff, el, er, csr, wE, n_dst, ne);

    agg_kernel<<<(n_dst + 3) / 4, 256, 0, stream>>>(fs, wE, roff, deg, csr, out, n_dst);
}